// Round 1
// baseline (15423.450 us; speedup 1.0000x reference)
//
#include <hip/hip_runtime.h>

// ---------------------------------------------------------------------------
// SSM evaluator: sequential scan over S=128 steps, 8192 independent rows.
// Persistent kernel: 512 blocks x 256 threads, 16 rows/block, z-state in LDS.
// Thread (r = tid&15, chunk = tid>>4): row r, column-chunk `chunk` of outputs.
// Activations in LDS column-major [k][r] -> broadcast reads, conflict-free.
// IAF masks folded into weight copies in d_ws by a pre-kernel (dense flows).
// ---------------------------------------------------------------------------

namespace {
constexpr int S  = 128;
constexpr int B  = 64;
constexpr int NC = 8;
constexpr int D  = 32;
constexpr int Z  = 64;
constexpr int H  = 128;   // == HI
constexpr int NF = 2;
constexpr int N  = 8192;  // NS * B
constexpr int RPB = 16;       // rows per block
constexpr int THREADS = 256;
constexpr int NCH = 16;       // column chunks (THREADS / RPB)

constexpr long SAMP_OFF = 0;
constexpr long FRAC_OFF = (long)S * 3 * NC * N;           // 25165824
constexpr long XLP_OFF  = FRAC_OFF + (long)S * NC * N;    // 33554432
constexpr long ZLP_OFF  = XLP_OFF + (long)S * 3 * NC * N; // 58720256

constexpr float HLOG2PI = 0.91893853320467274f;  // 0.5*log(2*pi)
}

__device__ __forceinline__ float sigm(float x) {
    return 1.0f / (1.0f + __expf(-x));
}
__device__ __forceinline__ float softplusf_(float x) {
    return fmaxf(x, 0.0f) + __logf(1.0f + __expf(-fabsf(x)));
}
__device__ __forceinline__ float logsigm(float x) {
    return fminf(x, 0.0f) - __logf(1.0f + __expf(-fabsf(x)));
}

#define FMA4(accp, a, wp)                                        \
    do {                                                         \
        const float4 w_ = *(const float4*)(wp);                  \
        (accp)[0] = fmaf((a), w_.x, (accp)[0]);                  \
        (accp)[1] = fmaf((a), w_.y, (accp)[1]);                  \
        (accp)[2] = fmaf((a), w_.z, (accp)[2]);                  \
        (accp)[3] = fmaf((a), w_.w, (accp)[3]);                  \
    } while (0)

#define FMA8(accp, a, wp)                                        \
    do {                                                         \
        FMA4((accp), (a), (wp));                                 \
        FMA4((accp) + 4, (a), (wp) + 4);                         \
    } while (0)

// --- Pre-kernel: fold the autoregressive masks into weight copies in ws. ---
// W1  layout [f][k<Z][j<H]   mask1[k][j] = (j%63 >= k)
// Wm/Ws layout [f][k<H][i<Z] mask2[k][i] = (k%63 <  i)
__global__ void mask_weights_kernel(const float* __restrict__ W1,
                                    const float* __restrict__ Wm,
                                    const float* __restrict__ Ws,
                                    float* __restrict__ ws)
{
    int idx = blockIdx.x * 256 + threadIdx.x;
    if (idx >= NF * Z * H) return;

    int j  = idx & (H - 1);
    int k1 = (idx >> 7) & (Z - 1);
    ws[idx] = W1[idx] * (((j % 63) >= k1) ? 1.0f : 0.0f);

    int i2 = idx & (Z - 1);
    int k2 = (idx >> 6) & (H - 1);
    float m2 = ((k2 % 63) < i2) ? 1.0f : 0.0f;
    ws[NF * Z * H + idx]     = Wm[idx] * m2;
    ws[2 * NF * Z * H + idx] = Ws[idx] * m2;
}

__global__ __launch_bounds__(THREADS, 2)
void ssm_scan_kernel(const float* __restrict__ input,
                     const float* __restrict__ eps,
                     const float* __restrict__ u,
                     const float* __restrict__ Wxh, const float* __restrict__ Wzh,
                     const float* __restrict__ bh,
                     const float* __restrict__ Wg,  const float* __restrict__ bg,
                     const float* __restrict__ Wp,  const float* __restrict__ bp,
                     const float* __restrict__ Wz,  const float* __restrict__ bz,
                     const float* __restrict__ Wsc, const float* __restrict__ bsc,
                     const float* __restrict__ W1m, const float* __restrict__ b1,
                     const float* __restrict__ Wmm, const float* __restrict__ bm,
                     const float* __restrict__ Wsm, const float* __restrict__ bs,
                     const float* __restrict__ We1, const float* __restrict__ be1,
                     const float* __restrict__ We2, const float* __restrict__ be2,
                     float* __restrict__ out)
{
    __shared__ float xT[D][RPB];
    __shared__ float zT[Z][RPB];
    __shared__ float hT[H][RPB];     // reused: h, hh (IAF), eh (emission)
    __shared__ float prT[Z][RPB];    // relu(prop)
    __shared__ float locT[Z][RPB];
    __shared__ float lpP[NCH][RPB];

    const int tid = threadIdx.x;
    const int r   = tid & (RPB - 1);
    const int ch  = tid >> 4;
    const int r0  = blockIdx.x * RPB;
    const int gr  = r0 + r;
    const int b0  = r0 & (B - 1);

    const int jH = ch * (H / NCH);        // 8 cols for H-sized outputs
    const int jZ = ch * (Z / NCH);        // 4 cols for Z-sized outputs
    const int jE = ch * ((4 * NC) / NCH); // 2 cols for the emission head

    // z0 = 0
    for (int i = tid; i < Z * RPB; i += THREADS) (&zT[0][0])[i] = 0.0f;

#pragma unroll 1
    for (int t = 0; t < S; ++t) {
        // stage x tile (D x RPB); x row for global row gr is input[t][gr % B]
        {
            int idx = tid;
#pragma unroll
            for (int rep = 0; rep < 2; ++rep, idx += THREADS) {
                int d = idx >> 4, rr = idx & (RPB - 1);
                xT[d][rr] = input[(t * B + b0 + rr) * D + d];
            }
        }
        __syncthreads();   // (also protects hT/lpP reads of previous step)

        float lp = 0.0f;   // per-step: base_lp - logdet contribution (own cols)

        // ---- phase 1: h = relu(x @ Wxh + z @ Wzh + bh) ----
        {
            float acc[8];
#pragma unroll
            for (int q = 0; q < 8; ++q) acc[q] = bh[jH + q];
#pragma unroll 4
            for (int k = 0; k < D; ++k) {
                float a = xT[k][r];
                FMA8(acc, a, Wxh + k * H + jH);
            }
#pragma unroll 4
            for (int k = 0; k < Z; ++k) {
                float a = zT[k][r];
                FMA8(acc, a, Wzh + k * H + jH);
            }
#pragma unroll
            for (int q = 0; q < 8; ++q) hT[jH + q][r] = fmaxf(acc[q], 0.0f);
        }
        __syncthreads();

        // ---- phase 2: gate, prop, z@Wz -> loc, relu(prop) ----
        {
            float ag[4], ap[4], az[4];
#pragma unroll
            for (int q = 0; q < 4; ++q) {
                ag[q] = bg[jZ + q];
                ap[q] = bp[jZ + q];
                az[q] = bz[jZ + q];
            }
#pragma unroll 4
            for (int k = 0; k < H; ++k) {
                float a = hT[k][r];
                FMA4(ag, a, Wg + k * Z + jZ);
                FMA4(ap, a, Wp + k * Z + jZ);
            }
#pragma unroll 4
            for (int k = 0; k < Z; ++k) {
                float a = zT[k][r];
                FMA4(az, a, Wz + k * Z + jZ);
            }
#pragma unroll
            for (int q = 0; q < 4; ++q) {
                float g = sigm(ag[q]);
                locT[jZ + q][r] = (1.0f - g) * az[q] + g * ap[q];
                prT[jZ + q][r]  = fmaxf(ap[q], 0.0f);
            }
        }
        __syncthreads();

        // ---- phase 3: scale = softplus(relu(prop) @ Wsc + bsc) + 1e-3,
        //               z = loc + scale * eps, base_lp accumulation ----
        {
            float as[4];
#pragma unroll
            for (int q = 0; q < 4; ++q) as[q] = bsc[jZ + q];
#pragma unroll 4
            for (int k = 0; k < Z; ++k) {
                float a = prT[k][r];
                FMA4(as, a, Wsc + k * Z + jZ);
            }
            const float4 ev = *(const float4*)(eps + (size_t)(t * N + gr) * Z + jZ);
            float e4[4] = {ev.x, ev.y, ev.z, ev.w};
#pragma unroll
            for (int q = 0; q < 4; ++q) {
                float sc = softplusf_(as[q]) + 0.001f;
                float e  = e4[q];
                zT[jZ + q][r] = locT[jZ + q][r] + sc * e;
                lp += -0.5f * e * e - __logf(sc) - HLOG2PI;
            }
        }
        __syncthreads();

        // ---- IAF flows (dense with pre-masked weights) ----
#pragma unroll 1
        for (int f = 0; f < NF; ++f) {
            {   // hh = relu(z @ W1m + b1)
                float acc[8];
#pragma unroll
                for (int q = 0; q < 8; ++q) acc[q] = b1[f * H + jH + q];
#pragma unroll 4
                for (int k = 0; k < Z; ++k) {
                    float a = zT[k][r];
                    FMA8(acc, a, W1m + (f * Z + k) * H + jH);
                }
#pragma unroll
                for (int q = 0; q < 8; ++q) hT[jH + q][r] = fmaxf(acc[q], 0.0f);
            }
            __syncthreads();
            {   // mu, sg; z = sg*z + (1-sg)*mu; logdet += log(sg)
                float am[4], ag2[4];
#pragma unroll
                for (int q = 0; q < 4; ++q) {
                    am[q]  = bm[f * Z + jZ + q];
                    ag2[q] = bs[f * Z + jZ + q] + 1.0f;
                }
#pragma unroll 4
                for (int k = 0; k < H; ++k) {
                    float a = hT[k][r];
                    FMA4(am,  a, Wmm + (f * H + k) * Z + jZ);
                    FMA4(ag2, a, Wsm + (f * H + k) * Z + jZ);
                }
#pragma unroll
                for (int q = 0; q < 4; ++q) {
                    float sg = sigm(ag2[q]);
                    float zo = zT[jZ + q][r];
                    zT[jZ + q][r] = sg * zo + (1.0f - sg) * am[q];
                    lp -= __logf(sg);
                }
            }
            __syncthreads();
        }

        lpP[ch][r] = lp;

        // ---- phase 8: eh = relu(z @ We1 + be1) ----
        {
            float acc[8];
#pragma unroll
            for (int q = 0; q < 8; ++q) acc[q] = be1[jH + q];
#pragma unroll 4
            for (int k = 0; k < Z; ++k) {
                float a = zT[k][r];
                FMA8(acc, a, We1 + k * H + jH);
            }
#pragma unroll
            for (int q = 0; q < 8; ++q) hT[jH + q][r] = fmaxf(acc[q], 0.0f);
        }
        __syncthreads();

        // ---- phase 9: e = eh @ We2 + be2, emission outputs, z_logprob ----
        {
            float acc[2];
#pragma unroll
            for (int q = 0; q < 2; ++q) acc[q] = be2[jE + q];
#pragma unroll 4
            for (int k = 0; k < H; ++k) {
                float a = hT[k][r];
                const float2 w = *(const float2*)(We2 + k * (4 * NC) + jE);
                acc[0] = fmaf(a, w.x, acc[0]);
                acc[1] = fmaf(a, w.y, acc[1]);
            }
#pragma unroll
            for (int q = 0; q < 2; ++q) {
                int col = jE + q;
                int c4 = col >> 3, nc = col & 7;
                float v = acc[q];
                if (c4 < 3) {
                    long plane = ((long)(t * 3 + c4) * NC + nc) * N + gr;
                    float sg = sigm(v);
                    float uv = u[plane];
                    bool hit = (uv < sg);
                    out[SAMP_OFF + plane] = hit ? 1.0f : 0.0f;
                    out[XLP_OFF + plane]  = hit ? logsigm(v) : logsigm(-v);
                } else {
                    out[FRAC_OFF + (long)(t * NC + nc) * N + gr] = sigm(v);
                }
            }
            if (tid < RPB) {
                float s = 0.0f;
#pragma unroll
                for (int q = 0; q < NCH; ++q) s += lpP[q][tid];
                out[ZLP_OFF + (long)t * N + r0 + tid] = s;
            }
        }
        // next iteration's x-load + barrier separates hT/lpP readers from writers
    }
}

extern "C" void kernel_launch(void* const* d_in, const int* in_sizes, int n_in,
                              void* d_out, int out_size, void* d_ws, size_t ws_size,
                              hipStream_t stream)
{
    const float* input = (const float*)d_in[0];
    const float* eps   = (const float*)d_in[1];
    const float* u     = (const float*)d_in[2];
    const float* Wxh   = (const float*)d_in[3];
    const float* Wzh   = (const float*)d_in[4];
    const float* bh    = (const float*)d_in[5];
    const float* Wg    = (const float*)d_in[6];
    const float* bg    = (const float*)d_in[7];
    const float* Wp    = (const float*)d_in[8];
    const float* bp    = (const float*)d_in[9];
    const float* Wz    = (const float*)d_in[10];
    const float* bz    = (const float*)d_in[11];
    const float* Wsc   = (const float*)d_in[12];
    const float* bsc   = (const float*)d_in[13];
    const float* W1    = (const float*)d_in[14];
    const float* b1    = (const float*)d_in[15];
    const float* Wm    = (const float*)d_in[16];
    const float* bm    = (const float*)d_in[17];
    const float* Ws    = (const float*)d_in[18];
    const float* bs    = (const float*)d_in[19];
    const float* We1   = (const float*)d_in[20];
    const float* be1   = (const float*)d_in[21];
    const float* We2   = (const float*)d_in[22];
    const float* be2   = (const float*)d_in[23];

    float* ws = (float*)d_ws;  // 3 * NF*Z*H floats = 192 KiB of masked weights

    hipLaunchKernelGGL(mask_weights_kernel, dim3((NF * Z * H + 255) / 256), dim3(256),
                       0, stream, W1, Wm, Ws, ws);

    hipLaunchKernelGGL(ssm_scan_kernel, dim3(N / RPB), dim3(THREADS), 0, stream,
                       input, eps, u, Wxh, Wzh, bh, Wg, bg, Wp, bp, Wz, bz, Wsc, bsc,
                       ws, b1, ws + NF * Z * H, bm, ws + 2 * NF * Z * H, bs,
                       We1, be1, We2, be2, (float*)d_out);
}

// Round 2
// 3326.154 us; speedup vs baseline: 4.6370x; 4.6370x over previous
//
#include <hip/hip_runtime.h>

// ---------------------------------------------------------------------------
// SSM evaluator, MFMA version.
// 256 blocks x 512 threads (8 waves), 32 rows/block, scan over S=128 steps.
// All matvecs via v_mfma_f32_16x16x32_f16 with hi/lo f16 split (3-term MFMA,
// lo-planes scaled x2048) for fp32-class precision.
// Activations live in LDS as f16 hi/lo planes, XOR-swizzled (^((row&7)<<4)).
// Weights are pre-masked, pre-transposed to [col][k], split hi/lo into d_ws.
// Wave w (rt=w>>2, c0=w&3) owns row-tile rt and col-tiles {c0, c0+4}.
// ---------------------------------------------------------------------------

typedef _Float16 f16x8 __attribute__((ext_vector_type(8)));
typedef _Float16 f16x4 __attribute__((ext_vector_type(4)));
typedef float    f32x4 __attribute__((ext_vector_type(4)));
typedef unsigned short u16;

#define MFMA16(a,b,c) __builtin_amdgcn_mfma_f32_16x16x32_f16((a),(b),(c),0,0,0)

namespace {
constexpr int S = 128;
constexpr long FRAC_OFF = 25165824L;   // S*3*NC*N
constexpr long XLP_OFF  = 33554432L;
constexpr long ZLP_OFF  = 58720256L;
constexpr float HLOG2PI = 0.91893853320467274f;
constexpr float INVLO   = 1.0f / 2048.0f;

// ws arena offsets (u16 elements). Layout per matrix: [col][k], hi then lo.
constexpr int C1HI = 0,      C1LO = 12288;   // [128][96]  = [Wxh;Wzh] stacked
constexpr int GPHI = 24576,  GPLO = 40960;   // [128][128] = [Wg|Wp]
constexpr int WZHI = 57344,  WZLO = 61440;   // [64][64]
constexpr int SCHI = 65536,  SCLO = 69632;   // [64][64]
constexpr int W1B  = 73728;                  // + f*16384 hi, +8192 lo  [128][64]
constexpr int MSB  = 106496;                 // + f*32768 hi, +16384 lo [128][128] = [Wm|Ws]
constexpr int E1HI = 172032, E1LO = 180224;  // [128][64]
constexpr int E2HI = 188416, E2LO = 192512;  // [32][128]
constexpr int XHI  = 196608, XLO  = 458752;  // [S*B*32] input split planes
}

__device__ __forceinline__ float sigm(float x)      { return 1.0f / (1.0f + __expf(-x)); }
__device__ __forceinline__ float softplusf_(float x){ return fmaxf(x, 0.f) + __logf(1.f + __expf(-fabsf(x))); }
__device__ __forceinline__ float logsigm(float x)   { return fminf(x, 0.f) - __logf(1.f + __expf(-fabsf(x))); }

__device__ __forceinline__ void split2(float v, _Float16& hi, _Float16& lo) {
    hi = (_Float16)v;
    lo = (_Float16)((v - (float)hi) * 2048.0f);
}

// A-fragment read from a swizzled LDS f16 plane: row = output row, k start.
__device__ __forceinline__ f16x8 rdA(const u16* t, int row, int k, int strideEls, int swm) {
    int byte = ((row * strideEls + k) * 2) ^ ((row & swm) << 4);
    return *(const f16x8*)((const char*)t + byte);
}
// B-fragment: weights [col][k], contiguous k.
__device__ __forceinline__ f16x8 ldB(const u16* wa, int base, int col, int K, int koff) {
    return *(const f16x8*)(wa + base + col * K + koff);
}

// dual-column-tile matmul job (col0, col1 = col0+64), A from one LDS tile
template<int K>
__device__ __forceinline__ void mm2(const u16* Ah, const u16* Al, int astride, int aswm,
                                    int arow, int kf, const u16* wa, int bHi, int bLo,
                                    int col0, int col1, float bias0, float bias1,
                                    f32x4& H0, f32x4& L0, f32x4& H1, f32x4& L1)
{
    H0 = (f32x4){bias0, bias0, bias0, bias0};
    H1 = (f32x4){bias1, bias1, bias1, bias1};
    L0 = (f32x4){0.f, 0.f, 0.f, 0.f};
    L1 = L0;
#pragma unroll
    for (int ks = 0; ks < K / 32; ++ks) {
        int k = ks * 32 + kf;
        f16x8 ah  = rdA(Ah, arow, k, astride, aswm);
        f16x8 al  = rdA(Al, arow, k, astride, aswm);
        f16x8 b0h = ldB(wa, bHi, col0, K, k);
        f16x8 b0l = ldB(wa, bLo, col0, K, k);
        f16x8 b1h = ldB(wa, bHi, col1, K, k);
        f16x8 b1l = ldB(wa, bLo, col1, K, k);
        H0 = MFMA16(ah, b0h, H0); L0 = MFMA16(ah, b0l, L0); L0 = MFMA16(al, b0h, L0);
        H1 = MFMA16(ah, b1h, H1); L1 = MFMA16(ah, b1l, L1); L1 = MFMA16(al, b1h, L1);
    }
}

template<int K>
__device__ __forceinline__ void mm1(const u16* Ah, const u16* Al, int astride, int aswm,
                                    int arow, int kf, const u16* wa, int bHi, int bLo,
                                    int col, float bias, f32x4& H, f32x4& L)
{
    H = (f32x4){bias, bias, bias, bias};
    L = (f32x4){0.f, 0.f, 0.f, 0.f};
#pragma unroll
    for (int ks = 0; ks < K / 32; ++ks) {
        int k = ks * 32 + kf;
        f16x8 ah = rdA(Ah, arow, k, astride, aswm);
        f16x8 al = rdA(Al, arow, k, astride, aswm);
        f16x8 bh = ldB(wa, bHi, col, K, k);
        f16x8 bl = ldB(wa, bLo, col, K, k);
        H = MFMA16(ah, bh, H); L = MFMA16(ah, bl, L); L = MFMA16(al, bh, L);
    }
}

// write C-fragment to swizzled hi/lo act tile (optionally relu)
template<bool RELU>
__device__ __forceinline__ void stAct(f32x4 H, f32x4 L, int rt, int lng, int col,
                                      u16* th, u16* tl, int strideEls, int swm)
{
#pragma unroll
    for (int q = 0; q < 4; ++q) {
        int row = rt * 16 + lng * 4 + q;
        float v = H[q] + L[q] * INVLO;
        if (RELU) v = fmaxf(v, 0.f);
        _Float16 hi, lo; split2(v, hi, lo);
        int byte = ((row * strideEls + col) * 2) ^ ((row & swm) << 4);
        *(_Float16*)((char*)th + byte) = hi;
        *(_Float16*)((char*)tl + byte) = lo;
    }
}
// write C-fragment to swizzled fp32 scratch
__device__ __forceinline__ void stScr(f32x4 H, f32x4 L, int rt, int lng, int col,
                                      float* s, int strideEls)
{
#pragma unroll
    for (int q = 0; q < 4; ++q) {
        int row = rt * 16 + lng * 4 + q;
        int byte = ((row * strideEls + col) * 4) ^ ((row & 7) << 4);
        *(float*)((char*)s + byte) = H[q] + L[q] * INVLO;
    }
}
__device__ __forceinline__ f32x4 rdS(const float* s, int strideEls, int row, int c) {
    int byte = ((row * strideEls + c) * 4) ^ ((row & 7) << 4);
    return *(const f32x4*)((const char*)s + byte);
}
__device__ __forceinline__ void wrS(float* s, int strideEls, int row, int c, f32x4 v) {
    int byte = ((row * strideEls + c) * 4) ^ ((row & 7) << 4);
    *(f32x4*)((char*)s + byte) = v;
}

// --- prep: build masked/stacked/transposed/split weights + split input ------
__global__ void prep_kernel(const float* __restrict__ input,
                            const float* __restrict__ Wxh, const float* __restrict__ Wzh,
                            const float* __restrict__ Wg,  const float* __restrict__ Wp,
                            const float* __restrict__ Wz,  const float* __restrict__ Wsc,
                            const float* __restrict__ W1,  const float* __restrict__ Wm,
                            const float* __restrict__ Ws_, const float* __restrict__ We1,
                            const float* __restrict__ We2, u16* __restrict__ wa)
{
    int idx = blockIdx.x * 256 + threadIdx.x;
    if (idx < 98304) {
        int hio = 0, loo = 0; float v = 0.f;
        int i = idx;
        if (i < 12288) {                       // C1 [128 col][96 k]: k<32 Wxh, else Wzh
            int col = i / 96, k = i % 96;
            v = (k < 32) ? Wxh[k * 128 + col] : Wzh[(k - 32) * 128 + col];
            hio = C1HI + i; loo = C1LO + i;
        } else if (i < 28672) { int j = i - 12288;   // GP [128][128]
            int col = j >> 7, k = j & 127;
            v = (col < 64) ? Wg[k * 64 + col] : Wp[k * 64 + col - 64];
            hio = GPHI + j; loo = GPLO + j;
        } else if (i < 32768) { int j = i - 28672;   // Wz [64][64]
            int col = j >> 6, k = j & 63; v = Wz[k * 64 + col];
            hio = WZHI + j; loo = WZLO + j;
        } else if (i < 36864) { int j = i - 32768;   // Wsc
            int col = j >> 6, k = j & 63; v = Wsc[k * 64 + col];
            hio = SCHI + j; loo = SCLO + j;
        } else if (i < 53248) { int j = i - 36864;   // W1 [2][128 col][64 k], mask1
            int f = j >> 13, jj = j & 8191;
            int col = jj >> 6, k = jj & 63;
            v = W1[(f * 64 + k) * 128 + col] * (((col % 63) >= k) ? 1.f : 0.f);
            hio = W1B + f * 16384 + jj; loo = hio + 8192;
        } else if (i < 86016) { int j = i - 53248;   // MS [2][128 col][128 k], mask2
            int f = j >> 14, jj = j & 16383;
            int col = jj >> 7, k = jj & 127;
            if (col < 64) v = Wm[(f * 128 + k) * 64 + col]       * (((k % 63) < col)        ? 1.f : 0.f);
            else { int c = col - 64;
                   v = Ws_[(f * 128 + k) * 64 + c]               * (((k % 63) < c)          ? 1.f : 0.f); }
            hio = MSB + f * 32768 + jj; loo = hio + 16384;
        } else if (i < 94208) { int j = i - 86016;   // We1 [128][64]
            int col = j >> 6, k = j & 63; v = We1[k * 128 + col];
            hio = E1HI + j; loo = E1LO + j;
        } else { int j = i - 94208;                  // We2 [32][128]
            int col = j >> 7, k = j & 127; v = We2[k * 32 + col];
            hio = E2HI + j; loo = E2LO + j;
        }
        _Float16 hi, lo; split2(v, hi, lo);
        wa[hio] = __builtin_bit_cast(u16, hi);
        wa[loo] = __builtin_bit_cast(u16, lo);
    } else {
        int j = idx - 98304;
        if (j < 262144) {                            // input split planes
            float v = input[j];
            _Float16 hi, lo; split2(v, hi, lo);
            wa[XHI + j] = __builtin_bit_cast(u16, hi);
            wa[XLO + j] = __builtin_bit_cast(u16, lo);
        }
    }
}

// --- main scan kernel -------------------------------------------------------
__global__ __launch_bounds__(512, 1)
void ssm_mfma_kernel(const float* __restrict__ eps, const float* __restrict__ u,
                     const float* __restrict__ bh,  const float* __restrict__ bg,
                     const float* __restrict__ bp,  const float* __restrict__ bz,
                     const float* __restrict__ bsc, const float* __restrict__ b1,
                     const float* __restrict__ bm,  const float* __restrict__ bs,
                     const float* __restrict__ be1, const float* __restrict__ be2,
                     const u16* __restrict__ wa, float* __restrict__ out)
{
    __shared__ u16 tXh[32 * 32],  tXl[32 * 32];    // x tile      (K=32,  swm 3)
    __shared__ u16 tZh[32 * 64],  tZl[32 * 64];    // z state     (K=64,  swm 7)
    __shared__ u16 tHh[32 * 128], tHl[32 * 128];   // h/hh/eh     (K=128, swm 7)
    __shared__ u16 tPh[32 * 64],  tPl[32 * 64];    // relu(prop)  (K=64,  swm 7)
    __shared__ float scr[32 * 128];                // fp32 scratch (stride 128)
    __shared__ float scr2[32 * 64];                // fp32 scratch (stride 64)
    __shared__ float lpS[16][32];

    const int tid = threadIdx.x;
    const int ln  = tid & 63, w = tid >> 6;
    const int lnc = ln & 15, lng = ln >> 4;
    const int rt  = w >> 2, c0 = w & 3;
    const int r0  = blockIdx.x * 32, b0 = r0 & 63;
    const int arow = rt * 16 + lnc;     // A-fragment row in the 32-row tile
    const int kf   = lng * 8;           // per-lane k offset inside a 32-slice
    const int crow = tid >> 4, cc = (tid & 15) * 4;  // combine mapping

    for (int i = tid; i < 32 * 64; i += 512) { tZh[i] = 0; tZl[i] = 0; }
    __syncthreads();

    for (int t = 0; t < S; ++t) {
        float lp = 0.f;

        // ---- P_x: stage input tile from pre-split planes ----
        {
            int rr = tid >> 4, d2 = (tid & 15) * 2;
            int ge = (t * 64 + b0 + rr) * 32 + d2;
            unsigned xh = *(const unsigned*)(wa + XHI + ge);
            unsigned xl = *(const unsigned*)(wa + XLO + ge);
            int byte = (rr * 64 + d2 * 2) ^ ((rr & 3) << 4);
            *(unsigned*)((char*)tXh + byte) = xh;
            *(unsigned*)((char*)tXl + byte) = xl;
        }
        __syncthreads();

        // ---- P_h: h = relu([x,z] @ C1 + bh) -> tileH ----
        {
            int col0 = c0 * 16 + lnc, col1 = col0 + 64;
            f32x4 H0 = {bh[col0], bh[col0], bh[col0], bh[col0]};
            f32x4 H1 = {bh[col1], bh[col1], bh[col1], bh[col1]};
            f32x4 L0 = {0.f, 0.f, 0.f, 0.f}, L1 = L0;
#pragma unroll
            for (int ks = 0; ks < 3; ++ks) {
                f16x8 ah, al;
                if (ks == 0) { ah = rdA(tXh, arow, kf, 32, 3); al = rdA(tXl, arow, kf, 32, 3); }
                else { ah = rdA(tZh, arow, (ks - 1) * 32 + kf, 64, 7);
                       al = rdA(tZl, arow, (ks - 1) * 32 + kf, 64, 7); }
                int k = ks * 32 + kf;
                f16x8 b0h = ldB(wa, C1HI, col0, 96, k), b0l = ldB(wa, C1LO, col0, 96, k);
                f16x8 b1h = ldB(wa, C1HI, col1, 96, k), b1l = ldB(wa, C1LO, col1, 96, k);
                H0 = MFMA16(ah, b0h, H0); L0 = MFMA16(ah, b0l, L0); L0 = MFMA16(al, b0h, L0);
                H1 = MFMA16(ah, b1h, H1); L1 = MFMA16(ah, b1l, L1); L1 = MFMA16(al, b1h, L1);
            }
            stAct<true>(H0, L0, rt, lng, col0, tHh, tHl, 128, 7);
            stAct<true>(H1, L1, rt, lng, col1, tHh, tHl, 128, 7);
        }
        __syncthreads();

        // ---- P_gpz: [gate|prop] = h @ GP ; zwz = z @ Wz -> scr, scr2 ----
        {
            int col0 = c0 * 16 + lnc, col1 = col0 + 64;
            f32x4 H0, L0, H1, L1, ZH, ZL;
            mm2<128>(tHh, tHl, 128, 7, arow, kf, wa, GPHI, GPLO, col0, col1,
                     bg[col0], bp[col0], H0, L0, H1, L1);
            mm1<64>(tZh, tZl, 64, 7, arow, kf, wa, WZHI, WZLO, col0, bz[col0], ZH, ZL);
            stScr(H0, L0, rt, lng, col0, scr, 128);
            stScr(H1, L1, rt, lng, col1, scr, 128);
            stScr(ZH, ZL, rt, lng, col0, scr2, 64);
        }
        __syncthreads();

        // ---- C1: gate/loc/relu(prop) ----
        {
            f32x4 gp4 = rdS(scr, 128, crow, cc);
            f32x4 pr4 = rdS(scr, 128, crow, cc + 64);
            f32x4 zz4 = rdS(scr2, 64, crow, cc);
            f16x4 ph, pl; f32x4 loc4;
#pragma unroll
            for (int i = 0; i < 4; ++i) {
                float g = sigm(gp4[i]);
                loc4[i] = (1.f - g) * zz4[i] + g * pr4[i];
                float rp = fmaxf(pr4[i], 0.f);
                _Float16 hi, lo; split2(rp, hi, lo); ph[i] = hi; pl[i] = lo;
            }
            wrS(scr2, 64, crow, cc, loc4);
            int byte = ((crow * 64 + cc) * 2) ^ ((crow & 7) << 4);
            *(f16x4*)((char*)tPh + byte) = ph;
            *(f16x4*)((char*)tPl + byte) = pl;
        }
        __syncthreads();

        // ---- P_sc: spre = relu(prop) @ Wsc + bsc -> scr[0:64] ----
        {
            int col = c0 * 16 + lnc;
            f32x4 SH, SL;
            mm1<64>(tPh, tPl, 64, 7, arow, kf, wa, SCHI, SCLO, col, bsc[col], SH, SL);
            stScr(SH, SL, rt, lng, col, scr, 128);
        }
        __syncthreads();

        // ---- C2: scale, z = loc + scale*eps, base_lp ----
        {
            f32x4 sp4  = rdS(scr, 128, crow, cc);
            f32x4 loc4 = rdS(scr2, 64, crow, cc);
            f32x4 e4   = *(const f32x4*)(eps + ((size_t)t * 8192 + r0 + crow) * 64 + cc);
            f16x4 zh, zl;
#pragma unroll
            for (int i = 0; i < 4; ++i) {
                float sc = softplusf_(sp4[i]) + 0.001f;
                float zv = loc4[i] + sc * e4[i];
                lp += -0.5f * e4[i] * e4[i] - __logf(sc) - HLOG2PI;
                _Float16 hi, lo; split2(zv, hi, lo); zh[i] = hi; zl[i] = lo;
            }
            int byte = ((crow * 64 + cc) * 2) ^ ((crow & 7) << 4);
            *(f16x4*)((char*)tZh + byte) = zh;
            *(f16x4*)((char*)tZl + byte) = zl;
        }
        __syncthreads();

        // ---- IAF flows ----
        for (int f = 0; f < 2; ++f) {
            {   // P_hh: hh = relu(z @ W1m + b1) -> tileH
                int col0 = c0 * 16 + lnc, col1 = col0 + 64;
                f32x4 H0, L0, H1, L1;
                mm2<64>(tZh, tZl, 64, 7, arow, kf, wa, W1B + f * 16384, W1B + f * 16384 + 8192,
                        col0, col1, b1[f * 128 + col0], b1[f * 128 + col1], H0, L0, H1, L1);
                stAct<true>(H0, L0, rt, lng, col0, tHh, tHl, 128, 7);
                stAct<true>(H1, L1, rt, lng, col1, tHh, tHl, 128, 7);
            }
            __syncthreads();
            {   // P_ms: [mu|spre] = hh @ MS -> scr
                int col0 = c0 * 16 + lnc, col1 = col0 + 64;
                f32x4 H0, L0, H1, L1;
                mm2<128>(tHh, tHl, 128, 7, arow, kf, wa, MSB + f * 32768, MSB + f * 32768 + 16384,
                         col0, col1, bm[f * 64 + col0], bs[f * 64 + col0], H0, L0, H1, L1);
                stScr(H0, L0, rt, lng, col0, scr, 128);
                stScr(H1, L1, rt, lng, col1, scr, 128);
            }
            __syncthreads();
            {   // C3: z = sg*z + (1-sg)*mu ; lp -= log(sg)
                f32x4 mu4 = rdS(scr, 128, crow, cc);
                f32x4 sp4 = rdS(scr, 128, crow, cc + 64);
                int byte = ((crow * 64 + cc) * 2) ^ ((crow & 7) << 4);
                f16x4 zh = *(const f16x4*)((const char*)tZh + byte);
                f16x4 zl = *(const f16x4*)((const char*)tZl + byte);
                f16x4 nzh, nzl;
#pragma unroll
                for (int i = 0; i < 4; ++i) {
                    float zv = (float)zh[i] + (float)zl[i] * INVLO;
                    float sg = sigm(sp4[i] + 1.0f);
                    float zn = sg * zv + (1.f - sg) * mu4[i];
                    lp -= __logf(sg);
                    _Float16 hi, lo; split2(zn, hi, lo); nzh[i] = hi; nzl[i] = lo;
                }
                *(f16x4*)((char*)tZh + byte) = nzh;
                *(f16x4*)((char*)tZl + byte) = nzl;
                if (f == 1) lpS[tid & 15][crow] = lp;
            }
            __syncthreads();
        }

        // ---- P_eh: eh = relu(z @ We1 + be1) -> tileH ----
        {
            int col0 = c0 * 16 + lnc, col1 = col0 + 64;
            f32x4 H0, L0, H1, L1;
            mm2<64>(tZh, tZl, 64, 7, arow, kf, wa, E1HI, E1LO, col0, col1,
                    be1[col0], be1[col1], H0, L0, H1, L1);
            stAct<true>(H0, L0, rt, lng, col0, tHh, tHl, 128, 7);
            stAct<true>(H1, L1, rt, lng, col1, tHh, tHl, 128, 7);
        }
        __syncthreads();

        // ---- P_e: e = eh @ We2 + be2, emission outputs; wave 2: zlp ----
        if (w == 0 || w == 1 || w == 4 || w == 5) {
            int ct = w & 1;
            int col = ct * 16 + lnc;           // 0..31
            f32x4 EH, EL;
            mm1<128>(tHh, tHl, 128, 7, arow, kf, wa, E2HI, E2LO, col, be2[col], EH, EL);
            int c4 = col >> 3, nc = col & 7;
            int gr0 = r0 + rt * 16 + lng * 4;
            f32x4 v4;
#pragma unroll
            for (int q = 0; q < 4; ++q) v4[q] = EH[q] + EL[q] * INVLO;
            if (c4 < 3) {
                long pl_ = ((long)(t * 3 + c4) * 8 + nc) * 8192 + gr0;
                f32x4 uu = *(const f32x4*)(u + pl_);
                f32x4 so, xo;
#pragma unroll
                for (int q = 0; q < 4; ++q) {
                    float sg = sigm(v4[q]);
                    bool hit = (uu[q] < sg);
                    so[q] = hit ? 1.f : 0.f;
                    xo[q] = hit ? logsigm(v4[q]) : logsigm(-v4[q]);
                }
                *(f32x4*)(out + pl_) = so;
                *(f32x4*)(out + XLP_OFF + pl_) = xo;
            } else {
                long pf = ((long)t * 8 + nc) * 8192 + gr0;
                f32x4 fo;
#pragma unroll
                for (int q = 0; q < 4; ++q) fo[q] = sigm(v4[q]);
                *(f32x4*)(out + FRAC_OFF + pf) = fo;
            }
        } else if (w == 2 && ln < 32) {
            float s = 0.f;
#pragma unroll
            for (int g = 0; g < 16; ++g) s += lpS[g][ln];
            out[ZLP_OFF + (long)t * 8192 + r0 + ln] = s;
        }
        // no barrier needed: next P_x only touches tileX, then barriers.
    }
}

extern "C" void kernel_launch(void* const* d_in, const int* in_sizes, int n_in,
                              void* d_out, int out_size, void* d_ws, size_t ws_size,
                              hipStream_t stream)
{
    const float* input = (const float*)d_in[0];
    const float* eps   = (const float*)d_in[1];
    const float* u     = (const float*)d_in[2];
    const float* Wxh   = (const float*)d_in[3];
    const float* Wzh   = (const float*)d_in[4];
    const float* bh    = (const float*)d_in[5];
    const float* Wg    = (const float*)d_in[6];
    const float* bg    = (const float*)d_in[7];
    const float* Wp    = (const float*)d_in[8];
    const float* bp    = (const float*)d_in[9];
    const float* Wz    = (const float*)d_in[10];
    const float* bz    = (const float*)d_in[11];
    const float* Wsc   = (const float*)d_in[12];
    const float* bsc   = (const float*)d_in[13];
    const float* W1    = (const float*)d_in[14];
    const float* b1    = (const float*)d_in[15];
    const float* Wm    = (const float*)d_in[16];
    const float* bm    = (const float*)d_in[17];
    const float* Ws    = (const float*)d_in[18];
    const float* bs    = (const float*)d_in[19];
    const float* We1   = (const float*)d_in[20];
    const float* be1   = (const float*)d_in[21];
    const float* We2   = (const float*)d_in[22];
    const float* be2   = (const float*)d_in[23];

    u16* wa = (u16*)d_ws;   // ~1.45 MB used

    hipLaunchKernelGGL(prep_kernel, dim3(1408), dim3(256), 0, stream,
                       input, Wxh, Wzh, Wg, Wp, Wz, Wsc, W1, Wm, Ws, We1, We2, wa);

    hipLaunchKernelGGL(ssm_mfma_kernel, dim3(256), dim3(512), 0, stream,
                       eps, u, bh, bg, bp, bz, bsc, b1, bm, bs, be1, be2,
                       wa, (float*)d_out);
}